// Round 6
// baseline (1108.673 us; speedup 1.0000x reference)
//
#include <hip/hip_runtime.h>

#define B_ 4
#define H_ 256
#define W_ 256
#define PXF4 9   // float4 per pixel: 8 data + 1 pad (144 B stride, 16-B aligned)

// f32 dot of 32-register array vs one pixel row held in 8 float4 regs.
// NOTE: numerics-load-bearing — accumulation structure verified (absmax 12.625).
__device__ __forceinline__ float dot32q(const float* a, const float4* q) {
    float s0 = 0.f, s1 = 0.f, s2 = 0.f, s3 = 0.f;
#pragma unroll
    for (int u = 0; u < 8; ++u) {
        float4 v = q[u];
        s0 += a[4*u+0] * v.x; s1 += a[4*u+1] * v.y;
        s2 += a[4*u+2] * v.z; s3 += a[4*u+3] * v.w;
    }
    return (s0 + s1) + (s2 + s3);
}

struct Signs { unsigned long long p0, n0; unsigned int p1, n1; };

__device__ __forceinline__ void phaseA_step(float ck, int k, const float4* s_kp,
                                            const float* __restrict__ mrw_p,
                                            float* mp, Signs& sg) {
    if (ck > 0.f)      { if (k < 64) sg.p0 |= 1ull << k; else sg.p1 |= 1u << (k - 64); }
    else if (ck < 0.f) { if (k < 64) sg.n0 |= 1ull << k; else sg.n1 |= 1u << (k - 64); }
    float4 kp = s_kp[k];
    float sn = (ck > 0.f) ? 1.f : ((ck < 0.f) ? -1.f : 0.f);
    float act  = kp.x * fabsf(ck) + kp.y * ck;
    float res  = act - kp.z;
    float dact = kp.x * sn + kp.y;
    float s = dact * res;
    const float* mr = mrw_p + k * 32;     // wave-uniform -> s_load
#pragma unroll
    for (int c = 0; c < 32; ++c) mp[c] += s * mr[c];
}

__device__ __forceinline__ void phaseC_step(float c3, int k, const float4* s_kp,
                                            const Signs& sg, float& den) {
    bool bp = (k < 64) ? ((sg.p0 >> k) & 1ull) : ((sg.p1 >> (k - 64)) & 1u);
    bool bn = (k < 64) ? ((sg.n0 >> k) & 1ull) : ((sg.n1 >> (k - 64)) & 1u);
    float sn = bp ? 1.f : (bn ? -1.f : 0.f);
    float4 kp = s_kp[k];
    float dact = kp.x * sn + kp.y;
    float s3 = dact * c3;
    den += s3 * s3;
}

// ============ 2-pixel-per-thread kernel: 32x16 px tile, 256 threads ============
#define TSX2 32
#define TSY2 16
#define TWX2 40
#define TWY2 24
#define NPX2 (TWX2 * TWY2)   // 960

__global__ void __launch_bounds__(256)
gocor2(const float* __restrict__ rf_g,
       const float* __restrict__ beta_p, const float* __restrict__ tw_p,
       const float* __restrict__ sw_p,  const float* __restrict__ mw_p,
       const float* __restrict__ mrw_p, const float* __restrict__ mrb_p,
       const float* __restrict__ lrw_p, const float* __restrict__ lrb_p,
       const float* __restrict__ wreg_p, const float* __restrict__ lsl_p,
       float* __restrict__ out)
{
    extern __shared__ float4 smem[];
    float4* s_rf   = smem;                    // NPX2 * PXF4
    float4* s_kp   = smem + NPX2 * PXF4;      // 81
    float*  s_bias = (float*)(s_kp + 81);     // [0..32) mr_b, [32..64) lr_b

    const int tid = threadIdx.x;
    const int tx = tid & 31, tyh = tid >> 5;          // 32 x 8 threads
    const int ty0 = tyh * 2;                          // each thread: pixels (tx,ty0),(tx,ty0+1)
    const int bx = blockIdx.x * TSX2, by = blockIdx.y * TSY2, bb = blockIdx.z;
    const float* rfb = rf_g + (size_t)bb * H_ * W_ * 32;

    // ---- stage f32 rf tile (+halo), zero outside image ----
    for (int idx = tid; idx < NPX2 * 8; idx += 256) {
        int u = idx & 7, p = idx >> 3;
        int ly = p / TWX2, lx = p - ly * TWX2;
        int gy = by + ly - 4, gx = bx + lx - 4;
        float4 v = make_float4(0.f, 0.f, 0.f, 0.f);
        if (gy >= 0 && gy < H_ && gx >= 0 && gx < W_)
            v = *(const float4*)(rfb + ((size_t)(gy * W_ + gx)) * 32 + u * 4);
        s_rf[p * PXF4 + u] = v;
    }

    // ---- per-block activation params (f32, faithful to reference) ----
    if (tid < 81) {
        int i = tid / 9, j = tid % 9;
        float di = (float)(i - 4), dj = (float)(j - 4);
        float dist = sqrtf(di * di + dj * dj);
        float y = 0.f, vp = 0.f, m = 0.f;
        for (int b = 0; b < 10; ++b) {
            float bd = 2.f * dist - (float)b;
            float val;
            if (i < 8) val = fmaxf(0.f, 1.f - fabsf(bd));        // triangular rows 0..7
            else       val = fminf(1.f, fmaxf(0.f, 1.f + bd));   // clipped row 8 (faithful)
            y  += val * tw_p[b];
            vp += val * sw_p[b];
            m  += val * mw_p[b];
        }
        float wm = 1.f / (1.f + expf(-m));
        s_kp[tid] = make_float4(vp * 0.5f * (1.f - wm),
                                vp * 0.5f * (1.f + wm),
                                vp * y, 0.f);
    }
    if (tid < 32)      s_bias[tid] = mrb_p[tid];
    else if (tid < 64) s_bias[tid] = lrb_p[tid - 32];

    float beta = beta_p[0];
    float wr   = wreg_p[0];
    float regw = fmaxf(wr * wr, (1e-5f * 1e-5f) / (32.f * 32.f));
    float step = expf(lsl_p[0]);

    __syncthreads();

    // ---- init both pixels: w = beta * rf / (mean(rf^2) + 1e-6) ----
    float w0[32], w1[32];
    {
#pragma unroll
        for (int px = 0; px < 2; ++px) {
            float* w = px ? w1 : w0;
            const float4* r = &s_rf[(((ty0 + px + 4) * TWX2) + (tx + 4)) * PXF4];
#pragma unroll
            for (int u = 0; u < 8; ++u) {
                float4 q = r[u];
                w[4*u+0] = q.x; w[4*u+1] = q.y; w[4*u+2] = q.z; w[4*u+3] = q.w;
            }
            float msq = 0.f;
#pragma unroll
            for (int c = 0; c < 32; ++c) msq += w[c] * w[c];
            float inv = beta / (msq * (1.f / 32.f) + 1e-6f);
#pragma unroll
            for (int c = 0; c < 32; ++c) w[c] *= inv;
        }
    }

    float mp0[32], mp1[32], fg0[32], fg1[32];

    for (int it = 0; it < 3; ++it) {
        // ---- Phase A: shared r-sweep; rows r=1..8 serve both pixels ----
        Signs sg0{0ull, 0ull, 0u, 0u}, sg1{0ull, 0ull, 0u, 0u};
#pragma unroll
        for (int c = 0; c < 32; ++c) { mp0[c] = s_bias[c]; mp1[c] = s_bias[c]; }
        for (int r = 0; r < 10; ++r) {
            const float4* rowp = &s_rf[((ty0 + r) * TWX2 + tx) * PXF4];
            for (int j = 0; j < 9; ++j) {
                float4 q[8];
                const float4* src = rowp + j * PXF4;
#pragma unroll
                for (int u = 0; u < 8; ++u) q[u] = src[u];
                if (r < 9) phaseA_step(dot32q(w0, q) * (1.f / 32.f), r * 9 + j,
                                       s_kp, mrw_p, mp0, sg0);
                if (r > 0) phaseA_step(dot32q(w1, q) * (1.f / 32.f), (r - 1) * 9 + j,
                                       s_kp, mrw_p, mp1, sg1);
            }
        }

        // ---- Phase B: filter_grad = regw*w + lcv(mapped, rf) @ lr_w + lr_b ----
#pragma unroll
        for (int c = 0; c < 32; ++c) {
            fg0[c] = s_bias[32 + c] + regw * w0[c];
            fg1[c] = s_bias[32 + c] + regw * w1[c];
        }
        for (int r = 0; r < 10; ++r) {
            const float4* rowp = &s_rf[((ty0 + r) * TWX2 + tx) * PXF4];
            for (int j = 0; j < 9; ++j) {
                float4 q[8];
                const float4* src = rowp + j * PXF4;
#pragma unroll
                for (int u = 0; u < 8; ++u) q[u] = src[u];
                if (r < 9) {
                    float ck = dot32q(mp0, q) * (1.f / 32.f);
                    const float* lr = lrw_p + (r * 9 + j) * 32;
#pragma unroll
                    for (int c = 0; c < 32; ++c) fg0[c] += ck * lr[c];
                }
                if (r > 0) {
                    float ck = dot32q(mp1, q) * (1.f / 32.f);
                    const float* lr = lrw_p + ((r - 1) * 9 + j) * 32;
#pragma unroll
                    for (int c = 0; c < 32; ++c) fg1[c] += ck * lr[c];
                }
            }
        }

        // ---- Phase C: alpha = sum(fg^2)/sum((dact*lcv(fg,rf))^2); w += alpha*step*fg ----
        float num0 = 0.f, num1 = 0.f;
#pragma unroll
        for (int c = 0; c < 32; ++c) { num0 += fg0[c] * fg0[c]; num1 += fg1[c] * fg1[c]; }
        float den0 = 0.f, den1 = 0.f;
        for (int r = 0; r < 10; ++r) {
            const float4* rowp = &s_rf[((ty0 + r) * TWX2 + tx) * PXF4];
            for (int j = 0; j < 9; ++j) {
                float4 q[8];
                const float4* src = rowp + j * PXF4;
#pragma unroll
                for (int u = 0; u < 8; ++u) q[u] = src[u];
                if (r < 9) phaseC_step(dot32q(fg0, q) * (1.f / 32.f), r * 9 + j,
                                       s_kp, sg0, den0);
                if (r > 0) phaseC_step(dot32q(fg1, q) * (1.f / 32.f), (r - 1) * 9 + j,
                                       s_kp, sg1, den1);
            }
        }
        float as0 = (num0 / den0) * step, as1 = (num1 / den1) * step;
#pragma unroll
        for (int c = 0; c < 32; ++c) { w0[c] += as0 * fg0[c]; w1[c] += as1 * fg1[c]; }
    }

    // ---- f32 output, float4 stores ----
#pragma unroll
    for (int px = 0; px < 2; ++px) {
        const float* w = px ? w1 : w0;
        float* o = out + (((size_t)bb * H_ + (by + ty0 + px)) * W_ + (bx + tx)) * 32;
#pragma unroll
        for (int u = 0; u < 8; ++u)
            *(float4*)(o + u * 4) = make_float4(w[4*u+0], w[4*u+1], w[4*u+2], w[4*u+3]);
    }
}

// ============ fallback: 1-pixel-per-thread 16x8 tile (round-4 proven) ============
__device__ __forceinline__ float dot32f(const float* a, const float4* r) {
    float s0 = 0.f, s1 = 0.f, s2 = 0.f, s3 = 0.f;
#pragma unroll
    for (int u = 0; u < 8; ++u) {
        float4 q = r[u];
        s0 += a[4*u+0] * q.x; s1 += a[4*u+1] * q.y;
        s2 += a[4*u+2] * q.z; s3 += a[4*u+3] * q.w;
    }
    return (s0 + s1) + (s2 + s3);
}

__global__ void __launch_bounds__(128)
gocor1(const float* __restrict__ rf_g,
       const float* __restrict__ beta_p, const float* __restrict__ tw_p,
       const float* __restrict__ sw_p,  const float* __restrict__ mw_p,
       const float* __restrict__ mrw_p, const float* __restrict__ mrb_p,
       const float* __restrict__ lrw_p, const float* __restrict__ lrb_p,
       const float* __restrict__ wreg_p, const float* __restrict__ lsl_p,
       float* __restrict__ out)
{
    constexpr int TWXc = 24, NPXc = 24 * 16;
    extern __shared__ float4 smem[];
    float4* s_rf  = smem;
    float4* s_kp  = smem + NPXc * PXF4;
    float*  s_bias = (float*)(s_kp + 81);

    const int tid = threadIdx.x;
    const int tx = tid & 15, ty = tid >> 4;
    const int bx = blockIdx.x * 16, by = blockIdx.y * 8, bb = blockIdx.z;
    const float* rfb = rf_g + (size_t)bb * H_ * W_ * 32;

    for (int idx = tid; idx < NPXc * 8; idx += 128) {
        int u = idx & 7, p = idx >> 3;
        int ly = p / TWXc, lx = p - ly * TWXc;
        int gy = by + ly - 4, gx = bx + lx - 4;
        float4 v = make_float4(0.f, 0.f, 0.f, 0.f);
        if (gy >= 0 && gy < H_ && gx >= 0 && gx < W_)
            v = *(const float4*)(rfb + ((size_t)(gy * W_ + gx)) * 32 + u * 4);
        s_rf[p * PXF4 + u] = v;
    }
    if (tid < 81) {
        int i = tid / 9, j = tid % 9;
        float di = (float)(i - 4), dj = (float)(j - 4);
        float dist = sqrtf(di * di + dj * dj);
        float y = 0.f, vp = 0.f, m = 0.f;
        for (int b = 0; b < 10; ++b) {
            float bd = 2.f * dist - (float)b;
            float val = (i < 8) ? fmaxf(0.f, 1.f - fabsf(bd))
                                : fminf(1.f, fmaxf(0.f, 1.f + bd));
            y += val * tw_p[b]; vp += val * sw_p[b]; m += val * mw_p[b];
        }
        float wm = 1.f / (1.f + expf(-m));
        s_kp[tid] = make_float4(vp * 0.5f * (1.f - wm), vp * 0.5f * (1.f + wm), vp * y, 0.f);
    }
    if (tid < 32)      s_bias[tid] = mrb_p[tid];
    else if (tid < 64) s_bias[tid] = lrb_p[tid - 32];

    float beta = beta_p[0], wr = wreg_p[0];
    float regw = fmaxf(wr * wr, (1e-5f * 1e-5f) / (32.f * 32.f));
    float step = expf(lsl_p[0]);
    __syncthreads();

    float w[32];
    {
        const float4* r = &s_rf[(((ty + 4) * TWXc) + (tx + 4)) * PXF4];
#pragma unroll
        for (int u = 0; u < 8; ++u) {
            float4 q = r[u];
            w[4*u+0] = q.x; w[4*u+1] = q.y; w[4*u+2] = q.z; w[4*u+3] = q.w;
        }
        float msq = 0.f;
#pragma unroll
        for (int c = 0; c < 32; ++c) msq += w[c] * w[c];
        float inv = beta / (msq * (1.f / 32.f) + 1e-6f);
#pragma unroll
        for (int c = 0; c < 32; ++c) w[c] *= inv;
    }

    float mp[32], fg[32];
    for (int it = 0; it < 3; ++it) {
        Signs sg{0ull, 0ull, 0u, 0u};
#pragma unroll
        for (int c = 0; c < 32; ++c) mp[c] = s_bias[c];
        for (int i = 0; i < 9; ++i) {
            int rowbase = (ty + i) * TWXc + tx;
            for (int j = 0; j < 9; ++j)
                phaseA_step(dot32f(w, &s_rf[(rowbase + j) * PXF4]) * (1.f / 32.f),
                            i * 9 + j, s_kp, mrw_p, mp, sg);
        }
#pragma unroll
        for (int c = 0; c < 32; ++c) fg[c] = s_bias[32 + c] + regw * w[c];
        for (int i = 0; i < 9; ++i) {
            int rowbase = (ty + i) * TWXc + tx;
            for (int j = 0; j < 9; ++j) {
                float ck = dot32f(mp, &s_rf[(rowbase + j) * PXF4]) * (1.f / 32.f);
                const float* lr = lrw_p + (i * 9 + j) * 32;
#pragma unroll
                for (int c = 0; c < 32; ++c) fg[c] += ck * lr[c];
            }
        }
        float num = 0.f;
#pragma unroll
        for (int c = 0; c < 32; ++c) num += fg[c] * fg[c];
        float den = 0.f;
        for (int i = 0; i < 9; ++i) {
            int rowbase = (ty + i) * TWXc + tx;
            for (int j = 0; j < 9; ++j)
                phaseC_step(dot32f(fg, &s_rf[(rowbase + j) * PXF4]) * (1.f / 32.f),
                            i * 9 + j, s_kp, sg, den);
        }
        float as = (num / den) * step;
#pragma unroll
        for (int c = 0; c < 32; ++c) w[c] += as * fg[c];
    }
    float* o = out + (((size_t)bb * H_ + (by + ty)) * W_ + (bx + tx)) * 32;
#pragma unroll
    for (int u = 0; u < 8; ++u)
        *(float4*)(o + u * 4) = make_float4(w[4*u+0], w[4*u+1], w[4*u+2], w[4*u+3]);
}

static const size_t BIG_SHM   = (size_t)(NPX2 * PXF4 + 81 + 16) * 16;   // 139,792 B
static const size_t SMALL_SHM = (size_t)(24 * 16 * PXF4 + 81 + 16) * 16; // 56,848 B

static bool query_big_path() {
    int dev = 0;
    if (hipGetDevice(&dev) != hipSuccess) return false;
    hipFuncSetAttribute(reinterpret_cast<const void*>(&gocor2),
                        hipFuncAttributeMaxDynamicSharedMemorySize, (int)BIG_SHM);
    int maxShm = 0;
    if (hipDeviceGetAttribute(&maxShm, hipDeviceAttributeMaxSharedMemoryPerBlock, dev) == hipSuccess &&
        (size_t)maxShm >= BIG_SHM)
        return true;
    hipFuncAttributes fa;
    if (hipFuncGetAttributes(&fa, reinterpret_cast<const void*>(&gocor2)) == hipSuccess &&
        (size_t)fa.maxDynamicSharedSizeBytes >= BIG_SHM)
        return true;
    return false;
}

extern "C" void kernel_launch(void* const* d_in, const int* in_sizes, int n_in,
                              void* d_out, int out_size, void* d_ws, size_t ws_size,
                              hipStream_t stream) {
    (void)d_ws; (void)ws_size; (void)in_sizes; (void)n_in; (void)out_size;
    static const bool use_big = query_big_path();   // resolved before graph capture

    const float* rf   = (const float*)d_in[0];
    const float* beta = (const float*)d_in[2];
    const float* tw   = (const float*)d_in[3];
    const float* sw   = (const float*)d_in[4];
    const float* mw   = (const float*)d_in[5];
    const float* mrw  = (const float*)d_in[6];
    const float* mrb  = (const float*)d_in[7];
    const float* lrw  = (const float*)d_in[8];
    const float* lrb  = (const float*)d_in[9];
    const float* wreg = (const float*)d_in[10];
    const float* lsl  = (const float*)d_in[11];
    float* o = (float*)d_out;

    if (use_big) {
        dim3 grid(W_ / TSX2, H_ / TSY2, B_);
        hipLaunchKernelGGL(gocor2, grid, dim3(256), BIG_SHM, stream,
                           rf, beta, tw, sw, mw, mrw, mrb, lrw, lrb, wreg, lsl, o);
    } else {
        dim3 grid(W_ / 16, H_ / 8, B_);
        hipLaunchKernelGGL(gocor1, grid, dim3(128), SMALL_SHM, stream,
                           rf, beta, tw, sw, mw, mrw, mrb, lrw, lrb, wreg, lsl, o);
    }
}